// Round 2
// baseline (3000.500 us; speedup 1.0000x reference)
//
#include <hip/hip_runtime.h>
#include <math.h>

// SpeMamba encoder: B=16, L=512, EMB=256, TOKEN_NUM=8, GC=32, DI=64, DS=16,
// DCONV=4, DTR=2, GN_GROUPS=4, LAYERS=4.
// h kept as [B, L, 256]. Position n = b*512+l. u[t][c] = h[n*256 + t*32 + c].
//
// R1 lesson: private arrays (x[8], hs[16], a[16], ...) were demoted to scratch
// -> 1.8 GB HBM spill traffic per dispatch (110x algorithmic). This version
// uses ONLY named scalars for per-lane state (macros unroll t); scratch is
// structurally impossible.

#define NWAVE1 4096   // waves in k_mamba (1024 blocks * 4 waves)

__device__ __forceinline__ float sigf(float v)   { return 1.0f / (1.0f + __expf(-v)); }
__device__ __forceinline__ float siluf(float v)  { return v * sigf(v); }
__device__ __forceinline__ float softplusf(float v) { return (v > 20.0f) ? v : log1pf(__expf(v)); }

// One wave = one position. Lane = d_inner channel (0..63).
__global__ __launch_bounds__(256, 3)
void k_mamba(const float* __restrict__ hin, float* __restrict__ xr,
             const float* __restrict__ Wi_g, const float* __restrict__ Wc_g,
             const float* __restrict__ bc_g, const float* __restrict__ Wx_g,
             const float* __restrict__ Wdt_g, const float* __restrict__ bdt_g,
             const float* __restrict__ Alog_g, const float* __restrict__ D_g,
             const float* __restrict__ Wo_g)
{
    __shared__ __align__(16) float sm[12296];
    float* const sWi  = sm;          // [128][33] = 4224 (2-way free)
    float* const sWx  = sm + 4224;   // [34][68]  = 2312 (conflict-free for fi map)
    float* const sWoT = sm + 6536;   // [64][36]  = 2304 (WoT[e][c])
    float* const sScr = sm + 8840;   // 4 waves * 864

    const int tid = threadIdx.x;
    for (int i = tid; i < 128*32; i += 256) sWi[(i >> 5)*33 + (i & 31)] = Wi_g[i];
    for (int i = tid; i < 34*64;  i += 256) sWx[(i >> 6)*68 + (i & 63)] = Wx_g[i];
    for (int i = tid; i < 32*64;  i += 256) sWoT[(i & 63)*36 + (i >> 6)] = Wo_g[i];

    const int wav = tid >> 6;
    const int ln  = tid & 63;
    float* const xb   = sScr + wav*864;         // [8][68] x-tile (aliased by yb)
    float* const xdbl = sScr + wav*864 + 544;   // [8][40]: [B 0..15 | C 16..31 | dt 32..33]
    float* const ubuf = xdbl;                   // [8][32] alias (u dead before xdbl written)
    float* const yb   = xb;                     // alias   (xb dead before yb written)

    // lane-private constants
    const float4 cw4 = *(const float4*)(Wc_g + ln*4);
    const float  cb   = bc_g[ln];
    const float  wdt0 = Wdt_g[ln*2 + 0];
    const float  wdt1 = Wdt_g[ln*2 + 1];
    const float  bdt  = bdt_g[ln];
    const float  Dd   = D_g[ln];
    const float4 A0v = *(const float4*)(Alog_g + ln*16 + 0);
    const float4 A1v = *(const float4*)(Alog_g + ln*16 + 4);
    const float4 A2v = *(const float4*)(Alog_g + ln*16 + 8);
    const float4 A3v = *(const float4*)(Alog_g + ln*16 + 12);
    const float a0=-__expf(A0v.x), a1=-__expf(A0v.y), a2=-__expf(A0v.z), a3=-__expf(A0v.w);
    const float a4=-__expf(A1v.x), a5=-__expf(A1v.y), a6=-__expf(A1v.z), a7=-__expf(A1v.w);
    const float a8=-__expf(A2v.x), a9=-__expf(A2v.y), a10=-__expf(A2v.z), a11=-__expf(A2v.w);
    const float a12=-__expf(A3v.x), a13=-__expf(A3v.y), a14=-__expf(A3v.z), a15=-__expf(A3v.w);
    __syncthreads();

    const int gw = blockIdx.x*4 + wav;
    #pragma unroll 1
    for (int it = 0; it < 2; ++it) {
        const int p = gw + it*NWAVE1;

        // stage u (256 consecutive floats, coalesced)
        *(float4*)(ubuf + ln*4) = *(const float4*)(hin + (size_t)p*256 + ln*4);
        __syncthreads();

        // ---- in_proj: x[t] = sum_c u[t,c]*Wi[d,c]; z[t] = sum_c u[t,c]*Wi[64+d,c]
        float x0=0.f,x1=0.f,x2=0.f,x3=0.f,x4=0.f,x5=0.f,x6=0.f,x7=0.f;
        float z0=0.f,z1=0.f,z2=0.f,z3=0.f,z4=0.f,z5=0.f,z6=0.f,z7=0.f;
        for (int c0 = 0; c0 < 32; c0 += 4) {
            const float wx0 = sWi[ln*33 + c0+0], wx1 = sWi[ln*33 + c0+1];
            const float wx2 = sWi[ln*33 + c0+2], wx3 = sWi[ln*33 + c0+3];
            const float wz0 = sWi[(64+ln)*33 + c0+0], wz1 = sWi[(64+ln)*33 + c0+1];
            const float wz2 = sWi[(64+ln)*33 + c0+2], wz3 = sWi[(64+ln)*33 + c0+3];
#define IPROJ_T(t) { const float4 u4 = *(const float4*)(ubuf + t*32 + c0); \
            x##t = fmaf(u4.x,wx0,fmaf(u4.y,wx1,fmaf(u4.z,wx2,fmaf(u4.w,wx3,x##t)))); \
            z##t = fmaf(u4.x,wz0,fmaf(u4.y,wz1,fmaf(u4.z,wz2,fmaf(u4.w,wz3,z##t)))); }
            IPROJ_T(0) IPROJ_T(1) IPROJ_T(2) IPROJ_T(3)
            IPROJ_T(4) IPROJ_T(5) IPROJ_T(6) IPROJ_T(7)
#undef IPROJ_T
        }

        // ---- causal depthwise conv (k=4, left pad 3) + bias + silu
        {
            const float w0=cw4.x, w1=cw4.y, w2=cw4.z, w3=cw4.w;
            const float n0 = fmaf(w3,x0,cb);
            const float n1 = fmaf(w3,x1,fmaf(w2,x0,cb));
            const float n2 = fmaf(w3,x2,fmaf(w2,x1,fmaf(w1,x0,cb)));
            const float n3 = fmaf(w3,x3,fmaf(w2,x2,fmaf(w1,x1,fmaf(w0,x0,cb))));
            const float n4 = fmaf(w3,x4,fmaf(w2,x3,fmaf(w1,x2,fmaf(w0,x1,cb))));
            const float n5 = fmaf(w3,x5,fmaf(w2,x4,fmaf(w1,x3,fmaf(w0,x2,cb))));
            const float n6 = fmaf(w3,x6,fmaf(w2,x5,fmaf(w1,x4,fmaf(w0,x3,cb))));
            const float n7 = fmaf(w3,x7,fmaf(w2,x6,fmaf(w1,x5,fmaf(w0,x4,cb))));
            x0=siluf(n0); x1=siluf(n1); x2=siluf(n2); x3=siluf(n3);
            x4=siluf(n4); x5=siluf(n5); x6=siluf(n6); x7=siluf(n7);
        }

        // ---- stash x for cross-lane x_proj
        xb[0*68+ln]=x0; xb[1*68+ln]=x1; xb[2*68+ln]=x2; xb[3*68+ln]=x3;
        xb[4*68+ln]=x4; xb[5*68+ln]=x5; xb[6*68+ln]=x6; xb[7*68+ln]=x7;
        __syncthreads();

        // ---- x_proj: xdbl[t,f] = sum_e x[t,e]*Wx[f,e]; lane -> (fi = ln>>3, tt = ln&7)
        {
            const int fi = ln >> 3, tt = ln & 7;
            float p0 = 0.f, p1 = 0.f, p2 = 0.f, p3 = 0.f, p4 = 0.f;
            for (int e = 0; e < 64; e += 4) {
                const float4 x4v = *(const float4*)(xb + tt*68 + e);
                float4 w;
                w = *(const float4*)(sWx + (fi)*68 + e);
                p0 += x4v.x*w.x + x4v.y*w.y + x4v.z*w.z + x4v.w*w.w;
                w = *(const float4*)(sWx + (8+fi)*68 + e);
                p1 += x4v.x*w.x + x4v.y*w.y + x4v.z*w.z + x4v.w*w.w;
                w = *(const float4*)(sWx + (16+fi)*68 + e);
                p2 += x4v.x*w.x + x4v.y*w.y + x4v.z*w.z + x4v.w*w.w;
                w = *(const float4*)(sWx + (24+fi)*68 + e);
                p3 += x4v.x*w.x + x4v.y*w.y + x4v.z*w.z + x4v.w*w.w;
                if (fi < 2) {
                    w = *(const float4*)(sWx + (32+fi)*68 + e);
                    p4 += x4v.x*w.x + x4v.y*w.y + x4v.z*w.z + x4v.w*w.w;
                }
            }
            // slot(f): f<2 -> 32+f (dt), else f-2 (B: 0..15, C: 16..31)
            xdbl[tt*40 + ((fi < 2) ? (32 + fi) : (fi - 2))] = p0;
            xdbl[tt*40 + 6  + fi] = p1;
            xdbl[tt*40 + 14 + fi] = p2;
            xdbl[tt*40 + 22 + fi] = p3;
            if (fi < 2) xdbl[tt*40 + 30 + fi] = p4;
        }
        __syncthreads();

        // ---- dt_proj + softplus + selective scan + gate (all state in named scalars)
        {
            float h0=0.f,h1=0.f,h2=0.f,h3=0.f,h4=0.f,h5=0.f,h6=0.f,h7=0.f;
            float h8=0.f,h9=0.f,h10=0.f,h11=0.f,h12=0.f,h13=0.f,h14=0.f,h15=0.f;
#define SSTEP(aa,hh,Bc,Cc) { const float dA=__expf(del*aa); hh=fmaf(dA,hh,dx*Bc); y=fmaf(hh,Cc,y); }
#define SCAN_T(t) { \
            const float del = softplusf(fmaf(xdbl[t*40+32], wdt0, fmaf(xdbl[t*40+33], wdt1, bdt))); \
            const float dx = del * x##t; \
            float y = 0.f; \
            const float4 B0 = *(const float4*)(xdbl + t*40 + 0); \
            const float4 B1 = *(const float4*)(xdbl + t*40 + 4); \
            const float4 B2 = *(const float4*)(xdbl + t*40 + 8); \
            const float4 B3 = *(const float4*)(xdbl + t*40 + 12); \
            const float4 C0 = *(const float4*)(xdbl + t*40 + 16); \
            const float4 C1 = *(const float4*)(xdbl + t*40 + 20); \
            const float4 C2 = *(const float4*)(xdbl + t*40 + 24); \
            const float4 C3 = *(const float4*)(xdbl + t*40 + 28); \
            SSTEP(a0,h0,B0.x,C0.x)  SSTEP(a1,h1,B0.y,C0.y)  SSTEP(a2,h2,B0.z,C0.z)  SSTEP(a3,h3,B0.w,C0.w) \
            SSTEP(a4,h4,B1.x,C1.x)  SSTEP(a5,h5,B1.y,C1.y)  SSTEP(a6,h6,B1.z,C1.z)  SSTEP(a7,h7,B1.w,C1.w) \
            SSTEP(a8,h8,B2.x,C2.x)  SSTEP(a9,h9,B2.y,C2.y)  SSTEP(a10,h10,B2.z,C2.z) SSTEP(a11,h11,B2.w,C2.w) \
            SSTEP(a12,h12,B3.x,C3.x) SSTEP(a13,h13,B3.y,C3.y) SSTEP(a14,h14,B3.z,C3.z) SSTEP(a15,h15,B3.w,C3.w) \
            y = fmaf(x##t, Dd, y); \
            yb[t*68+ln] = y * siluf(z##t); }
            SCAN_T(0) SCAN_T(1) SCAN_T(2) SCAN_T(3)
            SCAN_T(4) SCAN_T(5) SCAN_T(6) SCAN_T(7)
#undef SCAN_T
#undef SSTEP
        }
        __syncthreads();

        // ---- out_proj: out[t,c] = sum_e y[t,e]*Wo[c,e]; lane -> (t = ln>>3, c4 = (ln&7)*4)
        {
            const int gt = ln >> 3;
            const int c4 = (ln & 7) * 4;
            float o0 = 0.f, o1 = 0.f, o2 = 0.f, o3 = 0.f;
            for (int e0 = 0; e0 < 64; e0 += 4) {
                const float4 y4 = *(const float4*)(yb + gt*68 + e0);
                float4 w;
                w = *(const float4*)(sWoT + (e0+0)*36 + c4);
                o0 = fmaf(y4.x, w.x, o0); o1 = fmaf(y4.x, w.y, o1);
                o2 = fmaf(y4.x, w.z, o2); o3 = fmaf(y4.x, w.w, o3);
                w = *(const float4*)(sWoT + (e0+1)*36 + c4);
                o0 = fmaf(y4.y, w.x, o0); o1 = fmaf(y4.y, w.y, o1);
                o2 = fmaf(y4.y, w.z, o2); o3 = fmaf(y4.y, w.w, o3);
                w = *(const float4*)(sWoT + (e0+2)*36 + c4);
                o0 = fmaf(y4.z, w.x, o0); o1 = fmaf(y4.z, w.y, o1);
                o2 = fmaf(y4.z, w.z, o2); o3 = fmaf(y4.z, w.w, o3);
                w = *(const float4*)(sWoT + (e0+3)*36 + c4);
                o0 = fmaf(y4.w, w.x, o0); o1 = fmaf(y4.w, w.y, o1);
                o2 = fmaf(y4.w, w.z, o2); o3 = fmaf(y4.w, w.w, o3);
            }
            float4 o; o.x = o0; o.y = o1; o.z = o2; o.w = o3;
            *(float4*)(xr + (size_t)p*256 + gt*32 + c4) = o;
        }
        // no trailing barrier: scratch is wave-private; loop-top barrier re-syncs
    }
}

// GroupNorm stats: one block per (b, g); reduce 512 positions x 64 channels.
__global__ void k_gnstats(const float* __restrict__ xr, float* __restrict__ stats)
{
    const int b = blockIdx.x >> 2, g = blockIdx.x & 3;
    const int tid = threadIdx.x;
    const float* base = xr + (size_t)b*512*256 + g*64;
    float s = 0.f, ss = 0.f;
    for (int i = tid; i < 512*16; i += 256) {
        const int l = i >> 4, c4 = (i & 15) * 4;
        const float4 v = *(const float4*)(base + (size_t)l*256 + c4);
        s  += v.x + v.y + v.z + v.w;
        ss += v.x*v.x + v.y*v.y + v.z*v.z + v.w*v.w;
    }
    __shared__ float rs[256], rss[256];
    rs[tid] = s; rss[tid] = ss;
    __syncthreads();
    for (int off = 128; off > 0; off >>= 1) {
        if (tid < off) { rs[tid] += rs[tid+off]; rss[tid] += rss[tid+off]; }
        __syncthreads();
    }
    if (tid == 0) {
        const float mu  = rs[0] * (1.f/32768.f);
        const float var = rss[0] * (1.f/32768.f) - mu*mu;
        stats[blockIdx.x*2 + 0] = mu;
        stats[blockIdx.x*2 + 1] = rsqrtf(var + 1e-5f);
    }
}

// h_out = h_in + silu(gn(xr)); 4 elements per thread, float4.
__global__ void k_gnapply(const float* __restrict__ hin, const float* __restrict__ xrb,
                          const float* __restrict__ stats, const float* __restrict__ gamma,
                          const float* __restrict__ beta, float* __restrict__ hout)
{
    const int idx = blockIdx.x*256 + threadIdx.x;   // 0..524287
    const int e = idx * 4;
    const int c = e & 255;
    const int n = idx >> 6;     // position
    const int b = n >> 9;
    const int g = c >> 6;
    const float mu   = stats[(b*4+g)*2 + 0];
    const float rstd = stats[(b*4+g)*2 + 1];
    const float4 xv = *(const float4*)(xrb + e);
    float4 hv = *(const float4*)(hin + e);
    const float4 gm = *(const float4*)(gamma + c);
    const float4 bt = *(const float4*)(beta + c);
    hv.x += siluf(fmaf((xv.x - mu)*rstd, gm.x, bt.x));
    hv.y += siluf(fmaf((xv.y - mu)*rstd, gm.y, bt.y));
    hv.z += siluf(fmaf((xv.z - mu)*rstd, gm.z, bt.z));
    hv.w += siluf(fmaf((xv.w - mu)*rstd, gm.w, bt.w));
    *(float4*)(hout + e) = hv;
}

extern "C" void kernel_launch(void* const* d_in, const int* in_sizes, int n_in,
                              void* d_out, int out_size, void* d_ws, size_t ws_size,
                              hipStream_t stream)
{
    const float* x    = (const float*)d_in[0];
    const float* Wi   = (const float*)d_in[1];
    const float* Wc   = (const float*)d_in[2];
    const float* bc   = (const float*)d_in[3];
    const float* Wx   = (const float*)d_in[4];
    const float* Wdt  = (const float*)d_in[5];
    const float* bdt  = (const float*)d_in[6];
    const float* Alog = (const float*)d_in[7];
    const float* Dp   = (const float*)d_in[8];
    const float* Wo   = (const float*)d_in[9];
    const float* gam  = (const float*)d_in[10];
    const float* bet  = (const float*)d_in[11];

    float* out   = (float*)d_out;          // running h buffer ([B,L,256])
    float* xrb   = (float*)d_ws;           // 2,097,152 floats: mamba output per layer
    float* stats = xrb + 2097152;          // 128 floats: (mu, rstd) per (b, g)

    for (int layer = 0; layer < 4; ++layer) {
        const float* hi = (layer == 0) ? x : out;
        k_mamba<<<1024, 256, 0, stream>>>(hi, xrb,
            Wi + layer*4096, Wc + layer*256, bc + layer*64,
            Wx + layer*2176, Wdt + layer*128, bdt + layer*64,
            Alog + layer*1024, Dp + layer*64, Wo + layer*2048);
        k_gnstats<<<64, 256, 0, stream>>>(xrb, stats);
        k_gnapply<<<2048, 256, 0, stream>>>(hi, xrb, stats,
            gam + layer*256, bet + layer*256, out);
    }
}

// Round 3
// 1100.155 us; speedup vs baseline: 2.7273x; 2.7273x over previous
//
#include <hip/hip_runtime.h>
#include <math.h>

// SpeMamba encoder: B=16, L=512, EMB=256, TOKEN_NUM=8, GC=32, DI=64, DS=16,
// DCONV=4, DTR=2, GN_GROUPS=4, LAYERS=4.
// h kept as [B, L, 256]. Position n = b*512+l. u[t][c] = h[n*256 + t*32 + c].
//
// R2 lesson: __launch_bounds__(256,3) was interpreted as 6 waves/SIMD ->
// VGPR cap 84 (observed VGPR_Count=84=512/6 in BOTH R1 and R2) -> ~1.9 GB
// of scratch spill traffic per dispatch. This version drops the occupancy
// arg entirely; LDS (49.6 KB -> 3 blocks/CU) governs occupancy instead.

#define NWAVE1 4096   // waves in k_mamba (1024 blocks * 4 waves)

__device__ __forceinline__ float sigf(float v)   { return 1.0f / (1.0f + __expf(-v)); }
__device__ __forceinline__ float siluf(float v)  { return v * sigf(v); }
__device__ __forceinline__ float softplusf(float v) { return (v > 20.0f) ? v : log1pf(__expf(v)); }

// One wave = one position. Lane = d_inner channel (0..63).
__global__ __launch_bounds__(256)
void k_mamba(const float* __restrict__ hin, float* __restrict__ xr,
             const float* __restrict__ Wi_g, const float* __restrict__ Wc_g,
             const float* __restrict__ bc_g, const float* __restrict__ Wx_g,
             const float* __restrict__ Wdt_g, const float* __restrict__ bdt_g,
             const float* __restrict__ Alog_g, const float* __restrict__ D_g,
             const float* __restrict__ Wo_g)
{
    __shared__ __align__(16) float sm[12296];
    float* const sWi  = sm;          // [128][33] = 4224 (2-way free)
    float* const sWx  = sm + 4224;   // [34][68]  = 2312 (conflict-free for fi map)
    float* const sWoT = sm + 6536;   // [64][36]  = 2304 (WoT[e][c])
    float* const sScr = sm + 8840;   // 4 waves * 864

    const int tid = threadIdx.x;
    for (int i = tid; i < 128*32; i += 256) sWi[(i >> 5)*33 + (i & 31)] = Wi_g[i];
    for (int i = tid; i < 34*64;  i += 256) sWx[(i >> 6)*68 + (i & 63)] = Wx_g[i];
    for (int i = tid; i < 32*64;  i += 256) sWoT[(i & 63)*36 + (i >> 6)] = Wo_g[i];

    const int wav = tid >> 6;
    const int ln  = tid & 63;
    float* const xb   = sScr + wav*864;         // [8][68] x-tile (aliased by yb)
    float* const xdbl = sScr + wav*864 + 544;   // [8][40]: [B 0..15 | C 16..31 | dt 32..33]
    float* const ubuf = xdbl;                   // [8][32] alias (u dead before xdbl written)
    float* const yb   = xb;                     // alias   (xb dead before yb written)

    // lane-private constants
    const float4 cw4 = *(const float4*)(Wc_g + ln*4);
    const float  cb   = bc_g[ln];
    const float  wdt0 = Wdt_g[ln*2 + 0];
    const float  wdt1 = Wdt_g[ln*2 + 1];
    const float  bdt  = bdt_g[ln];
    const float  Dd   = D_g[ln];
    const float4 A0v = *(const float4*)(Alog_g + ln*16 + 0);
    const float4 A1v = *(const float4*)(Alog_g + ln*16 + 4);
    const float4 A2v = *(const float4*)(Alog_g + ln*16 + 8);
    const float4 A3v = *(const float4*)(Alog_g + ln*16 + 12);
    const float a0=-__expf(A0v.x), a1=-__expf(A0v.y), a2=-__expf(A0v.z), a3=-__expf(A0v.w);
    const float a4=-__expf(A1v.x), a5=-__expf(A1v.y), a6=-__expf(A1v.z), a7=-__expf(A1v.w);
    const float a8=-__expf(A2v.x), a9=-__expf(A2v.y), a10=-__expf(A2v.z), a11=-__expf(A2v.w);
    const float a12=-__expf(A3v.x), a13=-__expf(A3v.y), a14=-__expf(A3v.z), a15=-__expf(A3v.w);
    __syncthreads();

    const int gw = blockIdx.x*4 + wav;
    #pragma unroll 1
    for (int it = 0; it < 2; ++it) {
        const int p = gw + it*NWAVE1;

        // stage u (256 consecutive floats, coalesced)
        *(float4*)(ubuf + ln*4) = *(const float4*)(hin + (size_t)p*256 + ln*4);
        __syncthreads();

        // ---- in_proj: x[t] = sum_c u[t,c]*Wi[d,c]; z[t] = sum_c u[t,c]*Wi[64+d,c]
        float x0=0.f,x1=0.f,x2=0.f,x3=0.f,x4=0.f,x5=0.f,x6=0.f,x7=0.f;
        float z0=0.f,z1=0.f,z2=0.f,z3=0.f,z4=0.f,z5=0.f,z6=0.f,z7=0.f;
        for (int c0 = 0; c0 < 32; c0 += 4) {
            const float wx0 = sWi[ln*33 + c0+0], wx1 = sWi[ln*33 + c0+1];
            const float wx2 = sWi[ln*33 + c0+2], wx3 = sWi[ln*33 + c0+3];
            const float wz0 = sWi[(64+ln)*33 + c0+0], wz1 = sWi[(64+ln)*33 + c0+1];
            const float wz2 = sWi[(64+ln)*33 + c0+2], wz3 = sWi[(64+ln)*33 + c0+3];
#define IPROJ_T(t) { const float4 u4 = *(const float4*)(ubuf + t*32 + c0); \
            x##t = fmaf(u4.x,wx0,fmaf(u4.y,wx1,fmaf(u4.z,wx2,fmaf(u4.w,wx3,x##t)))); \
            z##t = fmaf(u4.x,wz0,fmaf(u4.y,wz1,fmaf(u4.z,wz2,fmaf(u4.w,wz3,z##t)))); }
            IPROJ_T(0) IPROJ_T(1) IPROJ_T(2) IPROJ_T(3)
            IPROJ_T(4) IPROJ_T(5) IPROJ_T(6) IPROJ_T(7)
#undef IPROJ_T
        }

        // ---- causal depthwise conv (k=4, left pad 3) + bias + silu
        {
            const float w0=cw4.x, w1=cw4.y, w2=cw4.z, w3=cw4.w;
            const float n0 = fmaf(w3,x0,cb);
            const float n1 = fmaf(w3,x1,fmaf(w2,x0,cb));
            const float n2 = fmaf(w3,x2,fmaf(w2,x1,fmaf(w1,x0,cb)));
            const float n3 = fmaf(w3,x3,fmaf(w2,x2,fmaf(w1,x1,fmaf(w0,x0,cb))));
            const float n4 = fmaf(w3,x4,fmaf(w2,x3,fmaf(w1,x2,fmaf(w0,x1,cb))));
            const float n5 = fmaf(w3,x5,fmaf(w2,x4,fmaf(w1,x3,fmaf(w0,x2,cb))));
            const float n6 = fmaf(w3,x6,fmaf(w2,x5,fmaf(w1,x4,fmaf(w0,x3,cb))));
            const float n7 = fmaf(w3,x7,fmaf(w2,x6,fmaf(w1,x5,fmaf(w0,x4,cb))));
            x0=siluf(n0); x1=siluf(n1); x2=siluf(n2); x3=siluf(n3);
            x4=siluf(n4); x5=siluf(n5); x6=siluf(n6); x7=siluf(n7);
        }

        // ---- stash x for cross-lane x_proj
        xb[0*68+ln]=x0; xb[1*68+ln]=x1; xb[2*68+ln]=x2; xb[3*68+ln]=x3;
        xb[4*68+ln]=x4; xb[5*68+ln]=x5; xb[6*68+ln]=x6; xb[7*68+ln]=x7;
        __syncthreads();

        // ---- x_proj: xdbl[t,f] = sum_e x[t,e]*Wx[f,e]; lane -> (fi = ln>>3, tt = ln&7)
        {
            const int fi = ln >> 3, tt = ln & 7;
            float p0 = 0.f, p1 = 0.f, p2 = 0.f, p3 = 0.f, p4 = 0.f;
            for (int e = 0; e < 64; e += 4) {
                const float4 x4v = *(const float4*)(xb + tt*68 + e);
                float4 w;
                w = *(const float4*)(sWx + (fi)*68 + e);
                p0 += x4v.x*w.x + x4v.y*w.y + x4v.z*w.z + x4v.w*w.w;
                w = *(const float4*)(sWx + (8+fi)*68 + e);
                p1 += x4v.x*w.x + x4v.y*w.y + x4v.z*w.z + x4v.w*w.w;
                w = *(const float4*)(sWx + (16+fi)*68 + e);
                p2 += x4v.x*w.x + x4v.y*w.y + x4v.z*w.z + x4v.w*w.w;
                w = *(const float4*)(sWx + (24+fi)*68 + e);
                p3 += x4v.x*w.x + x4v.y*w.y + x4v.z*w.z + x4v.w*w.w;
                if (fi < 2) {
                    w = *(const float4*)(sWx + (32+fi)*68 + e);
                    p4 += x4v.x*w.x + x4v.y*w.y + x4v.z*w.z + x4v.w*w.w;
                }
            }
            // slot(f): f<2 -> 32+f (dt), else f-2 (B: 0..15, C: 16..31)
            xdbl[tt*40 + ((fi < 2) ? (32 + fi) : (fi - 2))] = p0;
            xdbl[tt*40 + 6  + fi] = p1;
            xdbl[tt*40 + 14 + fi] = p2;
            xdbl[tt*40 + 22 + fi] = p3;
            if (fi < 2) xdbl[tt*40 + 30 + fi] = p4;
        }
        __syncthreads();

        // ---- dt_proj + softplus + selective scan + gate (all state in named scalars)
        {
            float h0=0.f,h1=0.f,h2=0.f,h3=0.f,h4=0.f,h5=0.f,h6=0.f,h7=0.f;
            float h8=0.f,h9=0.f,h10=0.f,h11=0.f,h12=0.f,h13=0.f,h14=0.f,h15=0.f;
#define SSTEP(aa,hh,Bc,Cc) { const float dA=__expf(del*aa); hh=fmaf(dA,hh,dx*Bc); y=fmaf(hh,Cc,y); }
#define SCAN_T(t) { \
            const float del = softplusf(fmaf(xdbl[t*40+32], wdt0, fmaf(xdbl[t*40+33], wdt1, bdt))); \
            const float dx = del * x##t; \
            float y = 0.f; \
            const float4 B0 = *(const float4*)(xdbl + t*40 + 0); \
            const float4 B1 = *(const float4*)(xdbl + t*40 + 4); \
            const float4 B2 = *(const float4*)(xdbl + t*40 + 8); \
            const float4 B3 = *(const float4*)(xdbl + t*40 + 12); \
            const float4 C0 = *(const float4*)(xdbl + t*40 + 16); \
            const float4 C1 = *(const float4*)(xdbl + t*40 + 20); \
            const float4 C2 = *(const float4*)(xdbl + t*40 + 24); \
            const float4 C3 = *(const float4*)(xdbl + t*40 + 28); \
            SSTEP(a0,h0,B0.x,C0.x)  SSTEP(a1,h1,B0.y,C0.y)  SSTEP(a2,h2,B0.z,C0.z)  SSTEP(a3,h3,B0.w,C0.w) \
            SSTEP(a4,h4,B1.x,C1.x)  SSTEP(a5,h5,B1.y,C1.y)  SSTEP(a6,h6,B1.z,C1.z)  SSTEP(a7,h7,B1.w,C1.w) \
            SSTEP(a8,h8,B2.x,C2.x)  SSTEP(a9,h9,B2.y,C2.y)  SSTEP(a10,h10,B2.z,C2.z) SSTEP(a11,h11,B2.w,C2.w) \
            SSTEP(a12,h12,B3.x,C3.x) SSTEP(a13,h13,B3.y,C3.y) SSTEP(a14,h14,B3.z,C3.z) SSTEP(a15,h15,B3.w,C3.w) \
            y = fmaf(x##t, Dd, y); \
            yb[t*68+ln] = y * siluf(z##t); }
            SCAN_T(0) SCAN_T(1) SCAN_T(2) SCAN_T(3)
            SCAN_T(4) SCAN_T(5) SCAN_T(6) SCAN_T(7)
#undef SCAN_T
#undef SSTEP
        }
        __syncthreads();

        // ---- out_proj: out[t,c] = sum_e y[t,e]*Wo[c,e]; lane -> (t = ln>>3, c4 = (ln&7)*4)
        {
            const int gt = ln >> 3;
            const int c4 = (ln & 7) * 4;
            float o0 = 0.f, o1 = 0.f, o2 = 0.f, o3 = 0.f;
            for (int e0 = 0; e0 < 64; e0 += 4) {
                const float4 y4 = *(const float4*)(yb + gt*68 + e0);
                float4 w;
                w = *(const float4*)(sWoT + (e0+0)*36 + c4);
                o0 = fmaf(y4.x, w.x, o0); o1 = fmaf(y4.x, w.y, o1);
                o2 = fmaf(y4.x, w.z, o2); o3 = fmaf(y4.x, w.w, o3);
                w = *(const float4*)(sWoT + (e0+1)*36 + c4);
                o0 = fmaf(y4.y, w.x, o0); o1 = fmaf(y4.y, w.y, o1);
                o2 = fmaf(y4.y, w.z, o2); o3 = fmaf(y4.y, w.w, o3);
                w = *(const float4*)(sWoT + (e0+2)*36 + c4);
                o0 = fmaf(y4.z, w.x, o0); o1 = fmaf(y4.z, w.y, o1);
                o2 = fmaf(y4.z, w.z, o2); o3 = fmaf(y4.z, w.w, o3);
                w = *(const float4*)(sWoT + (e0+3)*36 + c4);
                o0 = fmaf(y4.w, w.x, o0); o1 = fmaf(y4.w, w.y, o1);
                o2 = fmaf(y4.w, w.z, o2); o3 = fmaf(y4.w, w.w, o3);
            }
            float4 o; o.x = o0; o.y = o1; o.z = o2; o.w = o3;
            *(float4*)(xr + (size_t)p*256 + gt*32 + c4) = o;
        }
        // no trailing barrier: scratch is wave-private; loop-top barrier re-syncs
    }
}

// GroupNorm stats: one block per (b, g); reduce 512 positions x 64 channels.
__global__ void k_gnstats(const float* __restrict__ xr, float* __restrict__ stats)
{
    const int b = blockIdx.x >> 2, g = blockIdx.x & 3;
    const int tid = threadIdx.x;
    const float* base = xr + (size_t)b*512*256 + g*64;
    float s = 0.f, ss = 0.f;
    for (int i = tid; i < 512*16; i += 256) {
        const int l = i >> 4, c4 = (i & 15) * 4;
        const float4 v = *(const float4*)(base + (size_t)l*256 + c4);
        s  += v.x + v.y + v.z + v.w;
        ss += v.x*v.x + v.y*v.y + v.z*v.z + v.w*v.w;
    }
    __shared__ float rs[256], rss[256];
    rs[tid] = s; rss[tid] = ss;
    __syncthreads();
    for (int off = 128; off > 0; off >>= 1) {
        if (tid < off) { rs[tid] += rs[tid+off]; rss[tid] += rss[tid+off]; }
        __syncthreads();
    }
    if (tid == 0) {
        const float mu  = rs[0] * (1.f/32768.f);
        const float var = rss[0] * (1.f/32768.f) - mu*mu;
        stats[blockIdx.x*2 + 0] = mu;
        stats[blockIdx.x*2 + 1] = rsqrtf(var + 1e-5f);
    }
}

// h_out = h_in + silu(gn(xr)); 4 elements per thread, float4.
__global__ void k_gnapply(const float* __restrict__ hin, const float* __restrict__ xrb,
                          const float* __restrict__ stats, const float* __restrict__ gamma,
                          const float* __restrict__ beta, float* __restrict__ hout)
{
    const int idx = blockIdx.x*256 + threadIdx.x;   // 0..524287
    const int e = idx * 4;
    const int c = e & 255;
    const int n = idx >> 6;     // position
    const int b = n >> 9;
    const int g = c >> 6;
    const float mu   = stats[(b*4+g)*2 + 0];
    const float rstd = stats[(b*4+g)*2 + 1];
    const float4 xv = *(const float4*)(xrb + e);
    float4 hv = *(const float4*)(hin + e);
    const float4 gm = *(const float4*)(gamma + c);
    const float4 bt = *(const float4*)(beta + c);
    hv.x += siluf(fmaf((xv.x - mu)*rstd, gm.x, bt.x));
    hv.y += siluf(fmaf((xv.y - mu)*rstd, gm.y, bt.y));
    hv.z += siluf(fmaf((xv.z - mu)*rstd, gm.z, bt.z));
    hv.w += siluf(fmaf((xv.w - mu)*rstd, gm.w, bt.w));
    *(float4*)(hout + e) = hv;
}

extern "C" void kernel_launch(void* const* d_in, const int* in_sizes, int n_in,
                              void* d_out, int out_size, void* d_ws, size_t ws_size,
                              hipStream_t stream)
{
    const float* x    = (const float*)d_in[0];
    const float* Wi   = (const float*)d_in[1];
    const float* Wc   = (const float*)d_in[2];
    const float* bc   = (const float*)d_in[3];
    const float* Wx   = (const float*)d_in[4];
    const float* Wdt  = (const float*)d_in[5];
    const float* bdt  = (const float*)d_in[6];
    const float* Alog = (const float*)d_in[7];
    const float* Dp   = (const float*)d_in[8];
    const float* Wo   = (const float*)d_in[9];
    const float* gam  = (const float*)d_in[10];
    const float* bet  = (const float*)d_in[11];

    float* out   = (float*)d_out;          // running h buffer ([B,L,256])
    float* xrb   = (float*)d_ws;           // 2,097,152 floats: mamba output per layer
    float* stats = xrb + 2097152;          // 128 floats: (mu, rstd) per (b, g)

    for (int layer = 0; layer < 4; ++layer) {
        const float* hi = (layer == 0) ? x : out;
        k_mamba<<<1024, 256, 0, stream>>>(hi, xrb,
            Wi + layer*4096, Wc + layer*256, bc + layer*64,
            Wx + layer*2176, Wdt + layer*128, bdt + layer*64,
            Alog + layer*1024, Dp + layer*64, Wo + layer*2048);
        k_gnstats<<<64, 256, 0, stream>>>(xrb, stats);
        k_gnapply<<<2048, 256, 0, stream>>>(hi, xrb, stats,
            gam + layer*256, bet + layer*256, out);
    }
}

// Round 4
// 390.323 us; speedup vs baseline: 7.6872x; 2.8186x over previous
//
#include <hip/hip_runtime.h>
#include <math.h>

// SpeMamba encoder: B=16, L=512, EMB=256, TOKEN_NUM=8, GC=32, DI=64, DS=16,
// DCONV=4, DTR=2, GN_GROUPS=4, LAYERS=4.
// h kept as [B, L, 256]. Position n = b*512+l. u[t][c] = h[n*256 + t*32 + c].
//
// R3 lesson: even with named scalars and no launch-bounds cap, the scheduler
// hoisted all 64 scan ds_read_b128s (+ unrolled proj loops), blew past 256
// VGPRs and spilled ~470 MB/dispatch. Fix: sched_barrier(0) per scan t-step
// and #pragma unroll 1 on the projection loops to contain live ranges.

#define NWAVE1 4096   // waves in k_mamba (1024 blocks * 4 waves)

__device__ __forceinline__ float sigf(float v)   { return 1.0f / (1.0f + __expf(-v)); }
__device__ __forceinline__ float siluf(float v)  { return v * sigf(v); }
__device__ __forceinline__ float softplusf(float v) { return (v > 20.0f) ? v : log1pf(__expf(v)); }

// One wave = one position. Lane = d_inner channel (0..63).
__global__ __launch_bounds__(256)
void k_mamba(const float* __restrict__ hin, float* __restrict__ xr,
             const float* __restrict__ Wi_g, const float* __restrict__ Wc_g,
             const float* __restrict__ bc_g, const float* __restrict__ Wx_g,
             const float* __restrict__ Wdt_g, const float* __restrict__ bdt_g,
             const float* __restrict__ Alog_g, const float* __restrict__ D_g,
             const float* __restrict__ Wo_g)
{
    __shared__ __align__(16) float sm[12296];
    float* const sWi  = sm;          // [128][33] = 4224 (2-way free)
    float* const sWx  = sm + 4224;   // [34][68]  = 2312 (conflict-free for fi map)
    float* const sWoT = sm + 6536;   // [64][36]  = 2304 (WoT[e][c])
    float* const sScr = sm + 8840;   // 4 waves * 864

    const int tid = threadIdx.x;
    for (int i = tid; i < 128*32; i += 256) sWi[(i >> 5)*33 + (i & 31)] = Wi_g[i];
    for (int i = tid; i < 34*64;  i += 256) sWx[(i >> 6)*68 + (i & 63)] = Wx_g[i];
    for (int i = tid; i < 32*64;  i += 256) sWoT[(i & 63)*36 + (i >> 6)] = Wo_g[i];

    const int wav = tid >> 6;
    const int ln  = tid & 63;
    float* const xb   = sScr + wav*864;         // [8][68] x-tile (aliased by yb)
    float* const xdbl = sScr + wav*864 + 544;   // [8][40]: [B 0..15 | C 16..31 | dt 32..33]
    float* const ubuf = xdbl;                   // [8][32] alias (u dead before xdbl written)
    float* const yb   = xb;                     // alias   (xb dead before yb written)

    // lane-private constants
    const float4 cw4 = *(const float4*)(Wc_g + ln*4);
    const float  cb   = bc_g[ln];
    const float  wdt0 = Wdt_g[ln*2 + 0];
    const float  wdt1 = Wdt_g[ln*2 + 1];
    const float  bdt  = bdt_g[ln];
    const float  Dd   = D_g[ln];
    const float4 A0v = *(const float4*)(Alog_g + ln*16 + 0);
    const float4 A1v = *(const float4*)(Alog_g + ln*16 + 4);
    const float4 A2v = *(const float4*)(Alog_g + ln*16 + 8);
    const float4 A3v = *(const float4*)(Alog_g + ln*16 + 12);
    const float a0=-__expf(A0v.x), a1=-__expf(A0v.y), a2=-__expf(A0v.z), a3=-__expf(A0v.w);
    const float a4=-__expf(A1v.x), a5=-__expf(A1v.y), a6=-__expf(A1v.z), a7=-__expf(A1v.w);
    const float a8=-__expf(A2v.x), a9=-__expf(A2v.y), a10=-__expf(A2v.z), a11=-__expf(A2v.w);
    const float a12=-__expf(A3v.x), a13=-__expf(A3v.y), a14=-__expf(A3v.z), a15=-__expf(A3v.w);
    __syncthreads();

    const int gw = blockIdx.x*4 + wav;
    #pragma unroll 1
    for (int it = 0; it < 2; ++it) {
        const int p = gw + it*NWAVE1;

        // stage u (256 consecutive floats, coalesced)
        *(float4*)(ubuf + ln*4) = *(const float4*)(hin + (size_t)p*256 + ln*4);
        __syncthreads();

        // ---- in_proj: x[t] = sum_c u[t,c]*Wi[d,c]; z[t] = sum_c u[t,c]*Wi[64+d,c]
        float x0=0.f,x1=0.f,x2=0.f,x3=0.f,x4=0.f,x5=0.f,x6=0.f,x7=0.f;
        float z0=0.f,z1=0.f,z2=0.f,z3=0.f,z4=0.f,z5=0.f,z6=0.f,z7=0.f;
        #pragma unroll 1
        for (int c0 = 0; c0 < 32; c0 += 4) {
            const float wx0 = sWi[ln*33 + c0+0], wx1 = sWi[ln*33 + c0+1];
            const float wx2 = sWi[ln*33 + c0+2], wx3 = sWi[ln*33 + c0+3];
            const float wz0 = sWi[(64+ln)*33 + c0+0], wz1 = sWi[(64+ln)*33 + c0+1];
            const float wz2 = sWi[(64+ln)*33 + c0+2], wz3 = sWi[(64+ln)*33 + c0+3];
#define IPROJ_T(t) { const float4 u4 = *(const float4*)(ubuf + t*32 + c0); \
            x##t = fmaf(u4.x,wx0,fmaf(u4.y,wx1,fmaf(u4.z,wx2,fmaf(u4.w,wx3,x##t)))); \
            z##t = fmaf(u4.x,wz0,fmaf(u4.y,wz1,fmaf(u4.z,wz2,fmaf(u4.w,wz3,z##t)))); }
            IPROJ_T(0) IPROJ_T(1) IPROJ_T(2) IPROJ_T(3)
            IPROJ_T(4) IPROJ_T(5) IPROJ_T(6) IPROJ_T(7)
#undef IPROJ_T
        }

        // ---- causal depthwise conv (k=4, left pad 3) + bias + silu
        {
            const float w0=cw4.x, w1=cw4.y, w2=cw4.z, w3=cw4.w;
            const float n0 = fmaf(w3,x0,cb);
            const float n1 = fmaf(w3,x1,fmaf(w2,x0,cb));
            const float n2 = fmaf(w3,x2,fmaf(w2,x1,fmaf(w1,x0,cb)));
            const float n3 = fmaf(w3,x3,fmaf(w2,x2,fmaf(w1,x1,fmaf(w0,x0,cb))));
            const float n4 = fmaf(w3,x4,fmaf(w2,x3,fmaf(w1,x2,fmaf(w0,x1,cb))));
            const float n5 = fmaf(w3,x5,fmaf(w2,x4,fmaf(w1,x3,fmaf(w0,x2,cb))));
            const float n6 = fmaf(w3,x6,fmaf(w2,x5,fmaf(w1,x4,fmaf(w0,x3,cb))));
            const float n7 = fmaf(w3,x7,fmaf(w2,x6,fmaf(w1,x5,fmaf(w0,x4,cb))));
            x0=siluf(n0); x1=siluf(n1); x2=siluf(n2); x3=siluf(n3);
            x4=siluf(n4); x5=siluf(n5); x6=siluf(n6); x7=siluf(n7);
        }

        // ---- stash x for cross-lane x_proj
        xb[0*68+ln]=x0; xb[1*68+ln]=x1; xb[2*68+ln]=x2; xb[3*68+ln]=x3;
        xb[4*68+ln]=x4; xb[5*68+ln]=x5; xb[6*68+ln]=x6; xb[7*68+ln]=x7;
        __syncthreads();

        // ---- x_proj: xdbl[t,f] = sum_e x[t,e]*Wx[f,e]; lane -> (fi = ln>>3, tt = ln&7)
        {
            const int fi = ln >> 3, tt = ln & 7;
            float p0 = 0.f, p1 = 0.f, p2 = 0.f, p3 = 0.f, p4 = 0.f;
            #pragma unroll 1
            for (int e = 0; e < 64; e += 4) {
                const float4 x4v = *(const float4*)(xb + tt*68 + e);
                float4 w;
                w = *(const float4*)(sWx + (fi)*68 + e);
                p0 += x4v.x*w.x + x4v.y*w.y + x4v.z*w.z + x4v.w*w.w;
                w = *(const float4*)(sWx + (8+fi)*68 + e);
                p1 += x4v.x*w.x + x4v.y*w.y + x4v.z*w.z + x4v.w*w.w;
                w = *(const float4*)(sWx + (16+fi)*68 + e);
                p2 += x4v.x*w.x + x4v.y*w.y + x4v.z*w.z + x4v.w*w.w;
                w = *(const float4*)(sWx + (24+fi)*68 + e);
                p3 += x4v.x*w.x + x4v.y*w.y + x4v.z*w.z + x4v.w*w.w;
                if (fi < 2) {
                    w = *(const float4*)(sWx + (32+fi)*68 + e);
                    p4 += x4v.x*w.x + x4v.y*w.y + x4v.z*w.z + x4v.w*w.w;
                }
            }
            // slot(f): f<2 -> 32+f (dt), else f-2 (B: 0..15, C: 16..31)
            xdbl[tt*40 + ((fi < 2) ? (32 + fi) : (fi - 2))] = p0;
            xdbl[tt*40 + 6  + fi] = p1;
            xdbl[tt*40 + 14 + fi] = p2;
            xdbl[tt*40 + 22 + fi] = p3;
            if (fi < 2) xdbl[tt*40 + 30 + fi] = p4;
        }
        __syncthreads();

        // ---- dt_proj + softplus + selective scan + gate (all state in named scalars)
        // sched_barrier(0) per t-step keeps only one step's 8 ds_read_b128 in
        // flight -> live set ~130 VGPR instead of 256+spill.
        {
            float h0=0.f,h1=0.f,h2=0.f,h3=0.f,h4=0.f,h5=0.f,h6=0.f,h7=0.f;
            float h8=0.f,h9=0.f,h10=0.f,h11=0.f,h12=0.f,h13=0.f,h14=0.f,h15=0.f;
#define SSTEP(aa,hh,Bc,Cc) { const float dA=__expf(del*aa); hh=fmaf(dA,hh,dx*Bc); y=fmaf(hh,Cc,y); }
#define SCAN_T(t) { \
            const float del = softplusf(fmaf(xdbl[t*40+32], wdt0, fmaf(xdbl[t*40+33], wdt1, bdt))); \
            const float dx = del * x##t; \
            float y = 0.f; \
            const float4 B0 = *(const float4*)(xdbl + t*40 + 0); \
            const float4 B1 = *(const float4*)(xdbl + t*40 + 4); \
            const float4 B2 = *(const float4*)(xdbl + t*40 + 8); \
            const float4 B3 = *(const float4*)(xdbl + t*40 + 12); \
            const float4 C0 = *(const float4*)(xdbl + t*40 + 16); \
            const float4 C1 = *(const float4*)(xdbl + t*40 + 20); \
            const float4 C2 = *(const float4*)(xdbl + t*40 + 24); \
            const float4 C3 = *(const float4*)(xdbl + t*40 + 28); \
            SSTEP(a0,h0,B0.x,C0.x)  SSTEP(a1,h1,B0.y,C0.y)  SSTEP(a2,h2,B0.z,C0.z)  SSTEP(a3,h3,B0.w,C0.w) \
            SSTEP(a4,h4,B1.x,C1.x)  SSTEP(a5,h5,B1.y,C1.y)  SSTEP(a6,h6,B1.z,C1.z)  SSTEP(a7,h7,B1.w,C1.w) \
            SSTEP(a8,h8,B2.x,C2.x)  SSTEP(a9,h9,B2.y,C2.y)  SSTEP(a10,h10,B2.z,C2.z) SSTEP(a11,h11,B2.w,C2.w) \
            SSTEP(a12,h12,B3.x,C3.x) SSTEP(a13,h13,B3.y,C3.y) SSTEP(a14,h14,B3.z,C3.z) SSTEP(a15,h15,B3.w,C3.w) \
            y = fmaf(x##t, Dd, y); \
            yb[t*68+ln] = y * siluf(z##t); \
            __builtin_amdgcn_sched_barrier(0); }
            SCAN_T(0) SCAN_T(1) SCAN_T(2) SCAN_T(3)
            SCAN_T(4) SCAN_T(5) SCAN_T(6) SCAN_T(7)
#undef SCAN_T
#undef SSTEP
        }
        __syncthreads();

        // ---- out_proj: out[t,c] = sum_e y[t,e]*Wo[c,e]; lane -> (t = ln>>3, c4 = (ln&7)*4)
        {
            const int gt = ln >> 3;
            const int c4 = (ln & 7) * 4;
            float o0 = 0.f, o1 = 0.f, o2 = 0.f, o3 = 0.f;
            #pragma unroll 1
            for (int e0 = 0; e0 < 64; e0 += 4) {
                const float4 y4 = *(const float4*)(yb + gt*68 + e0);
                float4 w;
                w = *(const float4*)(sWoT + (e0+0)*36 + c4);
                o0 = fmaf(y4.x, w.x, o0); o1 = fmaf(y4.x, w.y, o1);
                o2 = fmaf(y4.x, w.z, o2); o3 = fmaf(y4.x, w.w, o3);
                w = *(const float4*)(sWoT + (e0+1)*36 + c4);
                o0 = fmaf(y4.y, w.x, o0); o1 = fmaf(y4.y, w.y, o1);
                o2 = fmaf(y4.y, w.z, o2); o3 = fmaf(y4.y, w.w, o3);
                w = *(const float4*)(sWoT + (e0+2)*36 + c4);
                o0 = fmaf(y4.z, w.x, o0); o1 = fmaf(y4.z, w.y, o1);
                o2 = fmaf(y4.z, w.z, o2); o3 = fmaf(y4.z, w.w, o3);
                w = *(const float4*)(sWoT + (e0+3)*36 + c4);
                o0 = fmaf(y4.w, w.x, o0); o1 = fmaf(y4.w, w.y, o1);
                o2 = fmaf(y4.w, w.z, o2); o3 = fmaf(y4.w, w.w, o3);
            }
            float4 o; o.x = o0; o.y = o1; o.z = o2; o.w = o3;
            *(float4*)(xr + (size_t)p*256 + gt*32 + c4) = o;
        }
        // no trailing barrier: scratch is wave-private; loop-top barrier re-syncs
    }
}

// GroupNorm stats: one block per (b, g); reduce 512 positions x 64 channels.
__global__ void k_gnstats(const float* __restrict__ xr, float* __restrict__ stats)
{
    const int b = blockIdx.x >> 2, g = blockIdx.x & 3;
    const int tid = threadIdx.x;
    const float* base = xr + (size_t)b*512*256 + g*64;
    float s = 0.f, ss = 0.f;
    for (int i = tid; i < 512*16; i += 256) {
        const int l = i >> 4, c4 = (i & 15) * 4;
        const float4 v = *(const float4*)(base + (size_t)l*256 + c4);
        s  += v.x + v.y + v.z + v.w;
        ss += v.x*v.x + v.y*v.y + v.z*v.z + v.w*v.w;
    }
    __shared__ float rs[256], rss[256];
    rs[tid] = s; rss[tid] = ss;
    __syncthreads();
    for (int off = 128; off > 0; off >>= 1) {
        if (tid < off) { rs[tid] += rs[tid+off]; rss[tid] += rss[tid+off]; }
        __syncthreads();
    }
    if (tid == 0) {
        const float mu  = rs[0] * (1.f/32768.f);
        const float var = rss[0] * (1.f/32768.f) - mu*mu;
        stats[blockIdx.x*2 + 0] = mu;
        stats[blockIdx.x*2 + 1] = rsqrtf(var + 1e-5f);
    }
}

// h_out = h_in + silu(gn(xr)); 4 elements per thread, float4.
__global__ void k_gnapply(const float* __restrict__ hin, const float* __restrict__ xrb,
                          const float* __restrict__ stats, const float* __restrict__ gamma,
                          const float* __restrict__ beta, float* __restrict__ hout)
{
    const int idx = blockIdx.x*256 + threadIdx.x;   // 0..524287
    const int e = idx * 4;
    const int c = e & 255;
    const int n = idx >> 6;     // position
    const int b = n >> 9;
    const int g = c >> 6;
    const float mu   = stats[(b*4+g)*2 + 0];
    const float rstd = stats[(b*4+g)*2 + 1];
    const float4 xv = *(const float4*)(xrb + e);
    float4 hv = *(const float4*)(hin + e);
    const float4 gm = *(const float4*)(gamma + c);
    const float4 bt = *(const float4*)(beta + c);
    hv.x += siluf(fmaf((xv.x - mu)*rstd, gm.x, bt.x));
    hv.y += siluf(fmaf((xv.y - mu)*rstd, gm.y, bt.y));
    hv.z += siluf(fmaf((xv.z - mu)*rstd, gm.z, bt.z));
    hv.w += siluf(fmaf((xv.w - mu)*rstd, gm.w, bt.w));
    *(float4*)(hout + e) = hv;
}

extern "C" void kernel_launch(void* const* d_in, const int* in_sizes, int n_in,
                              void* d_out, int out_size, void* d_ws, size_t ws_size,
                              hipStream_t stream)
{
    const float* x    = (const float*)d_in[0];
    const float* Wi   = (const float*)d_in[1];
    const float* Wc   = (const float*)d_in[2];
    const float* bc   = (const float*)d_in[3];
    const float* Wx   = (const float*)d_in[4];
    const float* Wdt  = (const float*)d_in[5];
    const float* bdt  = (const float*)d_in[6];
    const float* Alog = (const float*)d_in[7];
    const float* Dp   = (const float*)d_in[8];
    const float* Wo   = (const float*)d_in[9];
    const float* gam  = (const float*)d_in[10];
    const float* bet  = (const float*)d_in[11];

    float* out   = (float*)d_out;          // running h buffer ([B,L,256])
    float* xrb   = (float*)d_ws;           // 2,097,152 floats: mamba output per layer
    float* stats = xrb + 2097152;          // 128 floats: (mu, rstd) per (b, g)

    for (int layer = 0; layer < 4; ++layer) {
        const float* hi = (layer == 0) ? x : out;
        k_mamba<<<1024, 256, 0, stream>>>(hi, xrb,
            Wi + layer*4096, Wc + layer*256, bc + layer*64,
            Wx + layer*2176, Wdt + layer*128, bdt + layer*64,
            Alog + layer*1024, Dp + layer*64, Wo + layer*2048);
        k_gnstats<<<64, 256, 0, stream>>>(xrb, stats);
        k_gnapply<<<2048, 256, 0, stream>>>(hi, xrb, stats,
            gam + layer*256, bet + layer*256, out);
    }
}